// Round 3
// baseline (333.664 us; speedup 1.0000x reference)
//
#include <hip/hip_runtime.h>
#include <hip/hip_fp16.h>

// Problem constants
#define B_     8
#define NCAM   5
#define J_     15
#define H_     128
#define W_     240
#define NB     128000             // bins = 80*80*20
#define HW_    (H_ * W_)          // 30720
#define PAIR_DW ((H_ - 1) * W_)   // 30480 dwords: dword[y][x] = (f16 hm[y][x], f16 hm[y+1][x])
#define PAIR_G4 (PAIR_DW / 4)     // 7620 uint4 groups (240 % 4 == 0, no row straddle)
#define SMEM_BYTES (PAIR_DW * 4)  // 121920 B
#define TPB    640
#define NCHUNK 2
#define BPB    (NB / NCHUNK)      // 64000 bins per block
#define ITEMS  (BPB / TPB)        // 100 per thread
#define NBJ    (B_ * J_)          // 120
#define NBLK   (NBJ * NCHUNK)     // 240 blocks = 1 per CU, single round

typedef __fp16 fp16x2 __attribute__((ext_vector_type(2)));  // matches cvt_pkrtz return type

__device__ __forceinline__ unsigned int pkrtz(float lo, float hi) {
    fp16x2 h = __builtin_amdgcn_cvt_pkrtz(lo, hi);  // v_cvt_pkrtz_f16_f32, 1 op
    return __builtin_bit_cast(unsigned int, h);
}

// Bilinear weights with padding_mode='zeros' validity folded into a clamped
// 2x2 window (validated in round 1). Emits dword addr into the pair image and
// packed corner weights: w0 = (w00, w10) for column xc, w1 = (w01, w11) for xc+1.
__device__ __forceinline__ void bilinear_rec(float gx, float gy,
                                             unsigned int& addr,
                                             unsigned int& w0pk,
                                             unsigned int& w1pk) {
    const float ix = (gx + 1.0f) * (0.5f * (W_ - 1));
    const float iy = (gy + 1.0f) * (0.5f * (H_ - 1));
    const float x0f = floorf(ix);
    const float y0f = floorf(iy);
    const float wx1 = ix - x0f, wx0 = 1.0f - wx1;
    const float wy1 = iy - y0f, wy0 = 1.0f - wy1;
    const int x0 = (int)x0f;
    const int y0 = (int)y0f;
    const int xc = min(max(x0, 0), W_ - 2);
    const int yc = min(max(y0, 0), H_ - 2);
    const float vx0 = (x0 >= 0  && x0 <= W_ - 1) ? wx0 : 0.0f;
    const float vx1 = (x0 >= -1 && x0 <= W_ - 2) ? wx1 : 0.0f;
    const float vy0 = (y0 >= 0  && y0 <= H_ - 1) ? wy0 : 0.0f;
    const float vy1 = (y0 >= -1 && y0 <= H_ - 2) ? wy1 : 0.0f;
    const bool xhi = (x0 == W_ - 1);
    const bool xlo = (x0 == -1);
    const bool yhi = (y0 == H_ - 1);
    const bool ylo = (y0 == -1);
    const float a0 = (xhi ? 0.0f : vx0) + (xlo ? vx1 : 0.0f);
    const float a1 = (xhi ? vx0 : 0.0f) + (xlo ? 0.0f : vx1);
    const float b0 = (yhi ? 0.0f : vy0) + (ylo ? vy1 : 0.0f);
    const float b1 = (yhi ? vy0 : 0.0f) + (ylo ? 0.0f : vy1);
    addr = (unsigned int)(yc * W_ + xc);
    w0pk = pkrtz(a0 * b0, a0 * b1);
    w1pk = pkrtz(a1 * b0, a1 * b1);
}

// Precompute per-(cam,bin) records once per launch (they are reused by all
// 120 (b,j) pairs; previously recomputed 120x on the VALU).
__global__ __launch_bounds__(256) void weights_kernel(
    const float* __restrict__ sgrid,          // [NCAM, NB, 2]
    unsigned short* __restrict__ addr16,      // [NCAM*NB]
    uint2* __restrict__ wpk)                  // [NCAM*NB] = (w0pk, w1pk)
{
    const int i = blockIdx.x * 256 + threadIdx.x;
    if (i >= NCAM * NB) return;
    const float2 g = ((const float2*)sgrid)[i];
    unsigned int a, w0, w1;
    bilinear_rec(g.x, g.y, a, w0, w1);
    addr16[i] = (unsigned short)a;            // max 30478 < 65536
    wpk[i] = make_uint2(w0, w1);
}

// Stage heatmap image (f32, HxW) as row-pair f16 dwords into LDS.
__device__ __forceinline__ void stage_pairs(const float* __restrict__ img,
                                            unsigned int* s_pair, int tid) {
    const float4* __restrict__ src4 = (const float4*)img;
    uint4* dst = (uint4*)s_pair;
    for (int gi = tid; gi < PAIR_G4; gi += TPB) {
        const float4 a = src4[gi];            // row y, cols 4k..4k+3
        const float4 c = src4[gi + (W_ / 4)]; // row y+1, same cols
        uint4 d;
        d.x = pkrtz(a.x, c.x);
        d.y = pkrtz(a.y, c.y);
        d.z = pkrtz(a.z, c.z);
        d.w = pkrtz(a.w, c.w);
        dst[gi] = d;
    }
}

__device__ __forceinline__ float sample_pair(const unsigned int* s_pair,
                                             unsigned int a,
                                             unsigned int w0, unsigned int w1) {
    const unsigned int d0 = s_pair[a];        // (v00, v10)  -- ds_read2_b32 with d1
    const unsigned int d1 = s_pair[a + 1];    // (v01, v11)
    __half2 p = __hmul2(__builtin_bit_cast(__half2, d0),
                        __builtin_bit_cast(__half2, w0));
    p = __hfma2(__builtin_bit_cast(__half2, d1),
                __builtin_bit_cast(__half2, w1), p);
    return __low2float(p) + __high2float(p);
}

__global__ __launch_bounds__(TPB, 2) void project_kernel(
    const float* __restrict__ hm,             // [B, NCAM, J, H, W]
    const unsigned short* __restrict__ addr16,
    const uint2* __restrict__ wpk,
    float* __restrict__ out)                  // [B, J, NB]
{
    extern __shared__ unsigned int s_pair[];  // PAIR_DW dwords
    const int tid   = threadIdx.x;
    const int bj    = blockIdx.x % NBJ;       // chunk pair at bids bj, bj+120: 120%8==0 -> same XCD
    const int chunk = blockIdx.x / NBJ;
    const int b     = bj / J_;
    const int j     = bj % J_;
    const int bin0  = chunk * BPB;

    float acc[ITEMS];
#pragma unroll
    for (int it = 0; it < ITEMS; ++it) acc[it] = 0.0f;

    for (int n = 0; n < NCAM; ++n) {
        __syncthreads();
        stage_pairs(hm + (((size_t)b * NCAM + n) * J_ + j) * HW_, s_pair, tid);
        __syncthreads();
        const unsigned short* __restrict__ ap = addr16 + n * NB + bin0;
        const uint2* __restrict__ wp = wpk + n * NB + bin0;
#pragma unroll
        for (int it = 0; it < ITEMS; ++it) {
            const int r = it * TPB + tid;     // coalesced
            const unsigned int a = ap[r];
            const uint2 w = wp[r];
            acc[it] += sample_pair(s_pair, a, w.x, w.y);
        }
    }

    float* __restrict__ o = out + (size_t)bj * NB + bin0;
#pragma unroll
    for (int it = 0; it < ITEMS; ++it) {
        o[it * TPB + tid] = fminf(fmaxf(acc[it] * 0.2f, 0.0f), 1.0f);
    }
}

// Fallback (ws too small for records): inline weight computation, same LDS scheme.
__global__ __launch_bounds__(TPB, 2) void project_fallback(
    const float* __restrict__ hm,
    const float* __restrict__ sgrid,
    float* __restrict__ out)
{
    extern __shared__ unsigned int s_pair[];
    const int tid   = threadIdx.x;
    const int bj    = blockIdx.x % NBJ;
    const int chunk = blockIdx.x / NBJ;
    const int b     = bj / J_;
    const int j     = bj % J_;
    const int bin0  = chunk * BPB;

    float acc[ITEMS];
#pragma unroll
    for (int it = 0; it < ITEMS; ++it) acc[it] = 0.0f;

    for (int n = 0; n < NCAM; ++n) {
        __syncthreads();
        stage_pairs(hm + (((size_t)b * NCAM + n) * J_ + j) * HW_, s_pair, tid);
        __syncthreads();
        const float2* __restrict__ g2 = (const float2*)sgrid + n * NB + bin0;
#pragma unroll
        for (int it = 0; it < ITEMS; ++it) {
            const float2 g = g2[it * TPB + tid];
            unsigned int a, w0, w1;
            bilinear_rec(g.x, g.y, a, w0, w1);
            acc[it] += sample_pair(s_pair, a, w0, w1);
        }
    }

    float* __restrict__ o = out + (size_t)bj * NB + bin0;
#pragma unroll
    for (int it = 0; it < ITEMS; ++it) {
        o[it * TPB + tid] = fminf(fmaxf(acc[it] * 0.2f, 0.0f), 1.0f);
    }
}

extern "C" void kernel_launch(void* const* d_in, const int* in_sizes, int n_in,
                              void* d_out, int out_size, void* d_ws, size_t ws_size,
                              hipStream_t stream) {
    const float* hm = (const float*)d_in[0];   // [8,5,15,128,240] f32
    const float* sg = (const float*)d_in[1];   // [5,128000,2] f32
    float* out = (float*)d_out;                // [8,15,128000] f32

    (void)hipFuncSetAttribute((const void*)project_kernel,
                              hipFuncAttributeMaxDynamicSharedMemorySize, SMEM_BYTES);
    (void)hipFuncSetAttribute((const void*)project_fallback,
                              hipFuncAttributeMaxDynamicSharedMemorySize, SMEM_BYTES);

    const size_t addr_bytes = (size_t)NCAM * NB * sizeof(unsigned short); // 1.28 MB (8B aligned)
    const size_t wpk_bytes  = (size_t)NCAM * NB * sizeof(uint2);          // 5.12 MB
    if (ws_size >= addr_bytes + wpk_bytes) {
        unsigned short* addr16 = (unsigned short*)d_ws;
        uint2* wpk = (uint2*)((char*)d_ws + addr_bytes);
        weights_kernel<<<(NCAM * NB + 255) / 256, 256, 0, stream>>>(sg, addr16, wpk);
        project_kernel<<<NBLK, TPB, SMEM_BYTES, stream>>>(hm, addr16, wpk, out);
    } else {
        project_fallback<<<NBLK, TPB, SMEM_BYTES, stream>>>(hm, sg, out);
    }
}

// Round 4
// 243.846 us; speedup vs baseline: 1.3683x; 1.3683x over previous
//
#include <hip/hip_runtime.h>
#include <hip/hip_fp16.h>

// Problem constants
#define B_     8
#define NCAM   5
#define J_     15
#define H_     128
#define W_     240
#define NB     128000             // bins = 80*80*20
#define HW_    (H_ * W_)          // 30720
// Even-row-pair f16 image: dword[y2][x] = (f16 v(2*y2,x), f16 v(2*y2+1,x))
#define PAIR_ROWS (H_ / 2)        // 64
#define PAIR_DW  (PAIR_ROWS * W_) // 15360 dwords
#define SMEM_BYTES (PAIR_DW * 4)  // 61440 B -> 2 blocks/CU
#define PAIR_G4  (PAIR_DW / 4)    // 3840 uint4 groups
#define TPB    1024
#define NCHUNK 5
#define BPB    (NB / NCHUNK)      // 25600 bins per block
#define ITEMS  (BPB / TPB)        // 25 per thread -> acc[25] stays in VGPRs (R1-proven)
#define NBJ    (B_ * J_)          // 120
#define NBLK   (NBJ * NCHUNK)     // 600 blocks, 2 resident/CU

typedef __fp16 fp16x2 __attribute__((ext_vector_type(2)));

__device__ __forceinline__ unsigned int pkrtz(float lo, float hi) {
    fp16x2 h = __builtin_amdgcn_cvt_pkrtz(lo, hi);  // v_cvt_pkrtz_f16_f32
    return __builtin_bit_cast(unsigned int, h);
}

// Bilinear weights, padding_mode='zeros' validity folded into clamped 2x2
// window (validated R1). Camera-mean 1/5 is folded into the weights here.
// Encoding: addr16 = (yp*W + xc) | (odd << 14), yp = yc>>1, odd = yc&1.
//           w0pk = f16x2(0.2*a0*b0, 0.2*a0*b1)  (column xc;  lo=top row)
//           w1pk = f16x2(0.2*a1*b0, 0.2*a1*b1)  (column xc+1)
__device__ __forceinline__ void bilinear_rec(float gx, float gy,
                                             unsigned int& addr,
                                             unsigned int& w0pk,
                                             unsigned int& w1pk) {
    const float ix = (gx + 1.0f) * (0.5f * (W_ - 1));
    const float iy = (gy + 1.0f) * (0.5f * (H_ - 1));
    const float x0f = floorf(ix);
    const float y0f = floorf(iy);
    const float wx1 = ix - x0f, wx0 = 1.0f - wx1;
    const float wy1 = iy - y0f, wy0 = 1.0f - wy1;
    const int x0 = (int)x0f;
    const int y0 = (int)y0f;
    const int xc = min(max(x0, 0), W_ - 2);
    const int yc = min(max(y0, 0), H_ - 2);
    const float vx0 = (x0 >= 0  && x0 <= W_ - 1) ? wx0 : 0.0f;
    const float vx1 = (x0 >= -1 && x0 <= W_ - 2) ? wx1 : 0.0f;
    const float vy0 = (y0 >= 0  && y0 <= H_ - 1) ? wy0 : 0.0f;
    const float vy1 = (y0 >= -1 && y0 <= H_ - 2) ? wy1 : 0.0f;
    const bool xhi = (x0 == W_ - 1);
    const bool xlo = (x0 == -1);
    const bool yhi = (y0 == H_ - 1);
    const bool ylo = (y0 == -1);
    const float a0 = (xhi ? 0.0f : vx0) + (xlo ? vx1 : 0.0f);
    const float a1 = (xhi ? vx0 : 0.0f) + (xlo ? 0.0f : vx1);
    const float b0 = (yhi ? 0.0f : vy0) + (ylo ? vy1 : 0.0f);
    const float b1 = (yhi ? vy0 : 0.0f) + (ylo ? 0.0f : vy1);
    const int yp  = yc >> 1;
    const int odd = yc & 1;
    addr = (unsigned int)(yp * W_ + xc) | ((unsigned int)odd << 14);
    w0pk = pkrtz(0.2f * (a0 * b0), 0.2f * (a0 * b1));
    w1pk = pkrtz(0.2f * (a1 * b0), 0.2f * (a1 * b1));
}

__global__ __launch_bounds__(256) void weights_kernel(
    const float* __restrict__ sgrid,          // [NCAM, NB, 2]
    unsigned short* __restrict__ addr16,      // [NCAM*NB]
    uint2* __restrict__ wpk)                  // [NCAM*NB]
{
    const int i = blockIdx.x * 256 + threadIdx.x;
    if (i >= NCAM * NB) return;
    const float2 g = ((const float2*)sgrid)[i];
    unsigned int a, w0, w1;
    bilinear_rec(g.x, g.y, a, w0, w1);
    addr16[i] = (unsigned short)a;
    wpk[i] = make_uint2(w0, w1);
}

// Stage f32 HxW image as even-row-pair f16 dwords (61.4 KB).
__device__ __forceinline__ void stage_pairs(const float* __restrict__ img,
                                            unsigned int* s_img, int tid) {
    const float4* __restrict__ src4 = (const float4*)img;  // 60 groups per row
    uint4* dst = (uint4*)s_img;
    for (int gi = tid; gi < PAIR_G4; gi += TPB) {
        const int y2 = gi / (W_ / 4);
        const int xg = gi - y2 * (W_ / 4);
        const float4 t = src4[120 * y2 + xg];        // row 2*y2
        const float4 bo = src4[120 * y2 + 60 + xg];  // row 2*y2+1
        uint4 d;
        d.x = pkrtz(t.x, bo.x);
        d.y = pkrtz(t.y, bo.y);
        d.z = pkrtz(t.z, bo.z);
        d.w = pkrtz(t.w, bo.w);
        dst[gi] = d;
    }
}

// One bilinear sample from the even-pair image. Branchless odd-row handling:
//   even yc: col dword (top,bot) is a single pair dword; perm sel = identity.
//   odd  yc: top = hi half of pair row yp, bot = lo half of pair row yp+1.
__device__ __forceinline__ float sample_pair(const unsigned int* s_img,
                                             unsigned int a16,
                                             unsigned int w0, unsigned int w1) {
    const unsigned int odd = a16 >> 14;
    const unsigned int a   = a16 & 0x3FFFu;
    const unsigned int sel = 0x03020100u + odd * 0x02020202u;
    const unsigned int* base = s_img + a;
    const unsigned int d_a0 = base[0];              // ds_read2_b32 (cols xc, xc+1)
    const unsigned int d_a1 = base[1];
    const unsigned int off  = odd * (unsigned int)W_;
    const unsigned int d_b0 = base[off];            // second ds_read2_b32
    const unsigned int d_b1 = base[off + 1];
    const unsigned int c0 = __builtin_amdgcn_perm(d_b0, d_a0, sel); // (v00,v10)
    const unsigned int c1 = __builtin_amdgcn_perm(d_b1, d_a1, sel); // (v01,v11)
    __half2 p = __hmul2(__builtin_bit_cast(__half2, c0),
                        __builtin_bit_cast(__half2, w0));
    p = __hfma2(__builtin_bit_cast(__half2, c1),
                __builtin_bit_cast(__half2, w1), p);
    return __low2float(p) + __high2float(p);
}

__global__ __launch_bounds__(TPB, 8) void project_kernel(
    const float* __restrict__ hm,             // [B, NCAM, J, H, W]
    const unsigned short* __restrict__ addr16,
    const uint2* __restrict__ wpk,
    float* __restrict__ out)                  // [B, J, NB]
{
    extern __shared__ unsigned int s_img[];   // PAIR_DW dwords
    const int tid   = threadIdx.x;
    const int chunk = blockIdx.x % NCHUNK;
    const int bj    = blockIdx.x / NCHUNK;
    const int b     = bj / J_;
    const int j     = bj % J_;
    const int bin0  = chunk * BPB;

    float acc[ITEMS];
#pragma unroll
    for (int it = 0; it < ITEMS; ++it) acc[it] = 0.0f;

    for (int n = 0; n < NCAM; ++n) {
        __syncthreads();
        stage_pairs(hm + (((size_t)b * NCAM + n) * J_ + j) * HW_, s_img, tid);
        __syncthreads();
        const unsigned short* __restrict__ ap = addr16 + n * NB + bin0;
        const uint2* __restrict__ wp = wpk + n * NB + bin0;
#pragma unroll
        for (int it = 0; it < ITEMS; ++it) {
            const int r = it * TPB + tid;     // coalesced
            acc[it] += sample_pair(s_img, ap[r], wp[r].x, wp[r].y);
        }
    }

    float* __restrict__ o = out + (size_t)bj * NB + bin0;
#pragma unroll
    for (int it = 0; it < ITEMS; ++it) {
        o[it * TPB + tid] = fminf(fmaxf(acc[it], 0.0f), 1.0f);  // 1/5 folded in weights
    }
}

// Fallback (tiny ws): R1's validated f32-LDS kernel, inline weights.
#define FB_SMEM (HW_ * 4)
__global__ __launch_bounds__(TPB) void project_fallback(
    const float* __restrict__ hm,
    const float* __restrict__ sgrid,
    float* __restrict__ out)
{
    extern __shared__ float s_f32[];
    const int tid   = threadIdx.x;
    const int chunk = blockIdx.x % NCHUNK;
    const int bj    = blockIdx.x / NCHUNK;
    const int b     = bj / J_;
    const int j     = bj % J_;
    const int bin0  = chunk * BPB;

    float acc[ITEMS];
#pragma unroll
    for (int it = 0; it < ITEMS; ++it) acc[it] = 0.0f;

    for (int n = 0; n < NCAM; ++n) {
        __syncthreads();
        const float4* __restrict__ src =
            (const float4*)(hm + (((size_t)b * NCAM + n) * J_ + j) * HW_);
        float4* dst = (float4*)s_f32;
        for (int i = tid; i < HW_ / 4; i += TPB) dst[i] = src[i];
        __syncthreads();
        const float2* __restrict__ g2 = (const float2*)sgrid + n * NB + bin0;
#pragma unroll
        for (int it = 0; it < ITEMS; ++it) {
            const float2 g = g2[it * TPB + tid];
            const float ix = (g.x + 1.0f) * (0.5f * (W_ - 1));
            const float iy = (g.y + 1.0f) * (0.5f * (H_ - 1));
            const float x0f = floorf(ix), y0f = floorf(iy);
            const float wx1 = ix - x0f, wx0 = 1.0f - wx1;
            const float wy1 = iy - y0f, wy0 = 1.0f - wy1;
            const int x0 = (int)x0f, y0 = (int)y0f;
            const int xc = min(max(x0, 0), W_ - 2);
            const int yc = min(max(y0, 0), H_ - 2);
            const float vx0 = (x0 >= 0  && x0 <= W_ - 1) ? wx0 : 0.0f;
            const float vx1 = (x0 >= -1 && x0 <= W_ - 2) ? wx1 : 0.0f;
            const float vy0 = (y0 >= 0  && y0 <= H_ - 1) ? wy0 : 0.0f;
            const float vy1 = (y0 >= -1 && y0 <= H_ - 2) ? wy1 : 0.0f;
            const bool xhi = (x0 == W_ - 1), xlo = (x0 == -1);
            const bool yhi = (y0 == H_ - 1), ylo = (y0 == -1);
            const float a0 = (xhi ? 0.0f : vx0) + (xlo ? vx1 : 0.0f);
            const float a1 = (xhi ? vx0 : 0.0f) + (xlo ? 0.0f : vx1);
            const float b0 = (yhi ? 0.0f : vy0) + (ylo ? vy1 : 0.0f);
            const float b1 = (yhi ? vy0 : 0.0f) + (ylo ? 0.0f : vy1);
            const float* r0 = s_f32 + (yc * W_ + xc);
            acc[it] += b0 * (a0 * r0[0] + a1 * r0[1])
                     + b1 * (a0 * r0[W_] + a1 * r0[W_ + 1]);
        }
    }
    float* __restrict__ o = out + (size_t)bj * NB + bin0;
#pragma unroll
    for (int it = 0; it < ITEMS; ++it)
        o[it * TPB + tid] = fminf(fmaxf(acc[it] * 0.2f, 0.0f), 1.0f);
}

extern "C" void kernel_launch(void* const* d_in, const int* in_sizes, int n_in,
                              void* d_out, int out_size, void* d_ws, size_t ws_size,
                              hipStream_t stream) {
    const float* hm = (const float*)d_in[0];   // [8,5,15,128,240] f32
    const float* sg = (const float*)d_in[1];   // [5,128000,2] f32
    float* out = (float*)d_out;                // [8,15,128000] f32

    (void)hipFuncSetAttribute((const void*)project_fallback,
                              hipFuncAttributeMaxDynamicSharedMemorySize, FB_SMEM);

    const size_t addr_bytes = (size_t)NCAM * NB * sizeof(unsigned short); // 1.28 MB
    const size_t wpk_bytes  = (size_t)NCAM * NB * sizeof(uint2);          // 5.12 MB
    if (ws_size >= addr_bytes + wpk_bytes) {
        unsigned short* addr16 = (unsigned short*)d_ws;
        uint2* wpk = (uint2*)((char*)d_ws + addr_bytes);
        weights_kernel<<<(NCAM * NB + 255) / 256, 256, 0, stream>>>(sg, addr16, wpk);
        project_kernel<<<NBLK, TPB, SMEM_BYTES, stream>>>(hm, addr16, wpk, out);
    } else {
        project_fallback<<<NBLK, TPB, FB_SMEM, stream>>>(hm, sg, out);
    }
}

// Round 5
// 224.620 us; speedup vs baseline: 1.4855x; 1.0856x over previous
//
#include <hip/hip_runtime.h>
#include <hip/hip_fp16.h>

// Problem constants
#define B_     8
#define NCAM   5
#define J_     15
#define H_     128
#define W_     240
#define NB     128000             // bins = 80*80*20
#define HW_    (H_ * W_)          // 30720
// Even-row-pair f16 image: dword[y2][x] = (f16 v(2*y2,x), f16 v(2*y2+1,x))
#define PAIR_ROWS (H_ / 2)        // 64
#define PAIR_DW  (PAIR_ROWS * W_) // 15360 dwords
#define SMEM_BYTES (PAIR_DW * 4)  // 61440 B -> 2 blocks/CU (LDS-limited)
#define PAIR_G4  (PAIR_DW / 4)    // 3840 uint4 groups
#define TPB    1024
#define NCHUNK 8                  // 960 blocks: slot util 960/1024=94% (R4: 59%)
#define BPB    (NB / NCHUNK)      // 16000 bins per block
#define ITEMS  16                 // ceil(16000/1024); last row partially guarded
#define NBJ    (B_ * J_)          // 120
#define NBLK   (NBJ * NCHUNK)     // 960

typedef __fp16 fp16x2 __attribute__((ext_vector_type(2)));

__device__ __forceinline__ unsigned int pkrtz(float lo, float hi) {
    fp16x2 h = __builtin_amdgcn_cvt_pkrtz(lo, hi);  // v_cvt_pkrtz_f16_f32
    return __builtin_bit_cast(unsigned int, h);
}

// Bilinear weights, padding_mode='zeros' validity folded into clamped 2x2
// window (validated R1/R4). Camera-mean 1/5 folded into weights.
// addr16 = (yp*W + xc) | (odd << 14); w0pk=(0.2*a0*b0, 0.2*a0*b1), w1pk likewise for xc+1.
__device__ __forceinline__ void bilinear_rec(float gx, float gy,
                                             unsigned int& addr,
                                             unsigned int& w0pk,
                                             unsigned int& w1pk) {
    const float ix = (gx + 1.0f) * (0.5f * (W_ - 1));
    const float iy = (gy + 1.0f) * (0.5f * (H_ - 1));
    const float x0f = floorf(ix);
    const float y0f = floorf(iy);
    const float wx1 = ix - x0f, wx0 = 1.0f - wx1;
    const float wy1 = iy - y0f, wy0 = 1.0f - wy1;
    const int x0 = (int)x0f;
    const int y0 = (int)y0f;
    const int xc = min(max(x0, 0), W_ - 2);
    const int yc = min(max(y0, 0), H_ - 2);
    const float vx0 = (x0 >= 0  && x0 <= W_ - 1) ? wx0 : 0.0f;
    const float vx1 = (x0 >= -1 && x0 <= W_ - 2) ? wx1 : 0.0f;
    const float vy0 = (y0 >= 0  && y0 <= H_ - 1) ? wy0 : 0.0f;
    const float vy1 = (y0 >= -1 && y0 <= H_ - 2) ? wy1 : 0.0f;
    const bool xhi = (x0 == W_ - 1);
    const bool xlo = (x0 == -1);
    const bool yhi = (y0 == H_ - 1);
    const bool ylo = (y0 == -1);
    const float a0 = (xhi ? 0.0f : vx0) + (xlo ? vx1 : 0.0f);
    const float a1 = (xhi ? vx0 : 0.0f) + (xlo ? 0.0f : vx1);
    const float b0 = (yhi ? 0.0f : vy0) + (ylo ? vy1 : 0.0f);
    const float b1 = (yhi ? vy0 : 0.0f) + (ylo ? 0.0f : vy1);
    const int yp  = yc >> 1;
    const int odd = yc & 1;
    addr = (unsigned int)(yp * W_ + xc) | ((unsigned int)odd << 14);
    w0pk = pkrtz(0.2f * (a0 * b0), 0.2f * (a0 * b1));
    w1pk = pkrtz(0.2f * (a1 * b0), 0.2f * (a1 * b1));
}

__global__ __launch_bounds__(256) void weights_kernel(
    const float* __restrict__ sgrid,          // [NCAM, NB, 2]
    unsigned short* __restrict__ addr16,      // [NCAM*NB]
    uint2* __restrict__ wpk)                  // [NCAM*NB]
{
    const int i = blockIdx.x * 256 + threadIdx.x;
    if (i >= NCAM * NB) return;
    const float2 g = ((const float2*)sgrid)[i];
    unsigned int a, w0, w1;
    bilinear_rec(g.x, g.y, a, w0, w1);
    addr16[i] = (unsigned short)a;
    wpk[i] = make_uint2(w0, w1);
}

// Stage f32 HxW image as even-row-pair f16 dwords (61.4 KB).
__device__ __forceinline__ void stage_pairs(const float* __restrict__ img,
                                            unsigned int* s_img, int tid) {
    const float4* __restrict__ src4 = (const float4*)img;  // 60 groups per row
    uint4* dst = (uint4*)s_img;
    for (int gi = tid; gi < PAIR_G4; gi += TPB) {
        const int y2 = gi / (W_ / 4);
        const int xg = gi - y2 * (W_ / 4);
        const float4 t  = src4[120 * y2 + xg];       // row 2*y2
        const float4 bo = src4[120 * y2 + 60 + xg];  // row 2*y2+1
        uint4 d;
        d.x = pkrtz(t.x, bo.x);
        d.y = pkrtz(t.y, bo.y);
        d.z = pkrtz(t.z, bo.z);
        d.w = pkrtz(t.w, bo.w);
        dst[gi] = d;
    }
}

// One bilinear sample from the even-pair image (validated R4).
__device__ __forceinline__ float sample_pair(const unsigned int* s_img,
                                             unsigned int a16,
                                             unsigned int w0, unsigned int w1) {
    const unsigned int odd = a16 >> 14;
    const unsigned int a   = a16 & 0x3FFFu;
    const unsigned int sel = 0x03020100u + odd * 0x02020202u;
    const unsigned int* base = s_img + a;
    const unsigned int d_a0 = base[0];              // ds_read2_b32 (cols xc, xc+1)
    const unsigned int d_a1 = base[1];
    const unsigned int off  = odd * (unsigned int)W_;
    const unsigned int d_b0 = base[off];            // second ds_read2_b32
    const unsigned int d_b1 = base[off + 1];
    const unsigned int c0 = __builtin_amdgcn_perm(d_b0, d_a0, sel); // (v00,v10)
    const unsigned int c1 = __builtin_amdgcn_perm(d_b1, d_a1, sel); // (v01,v11)
    __half2 p = __hmul2(__builtin_bit_cast(__half2, c0),
                        __builtin_bit_cast(__half2, w0));
    p = __hfma2(__builtin_bit_cast(__half2, c1),
                __builtin_bit_cast(__half2, w1), p);
    return __low2float(p) + __high2float(p);
}

__global__ __launch_bounds__(TPB, 8) void project_kernel(
    const float* __restrict__ hm,             // [B, NCAM, J, H, W]
    const unsigned short* __restrict__ addr16,
    const uint2* __restrict__ wpk,
    float* __restrict__ out)                  // [B, J, NB]
{
    extern __shared__ unsigned int s_img[];   // PAIR_DW dwords
    const int tid   = threadIdx.x;
    // bj-major mapping: same-bj blocks at bids bj+120k; 120%8==0 -> same XCD,
    // so all 8 chunks of a (b,j) share one XCD's L2 for the staged images.
    const int bj    = blockIdx.x % NBJ;
    const int chunk = blockIdx.x / NBJ;
    const int b     = bj / J_;
    const int j     = bj % J_;
    const int bin0  = chunk * BPB;

    float acc[ITEMS];
#pragma unroll
    for (int it = 0; it < ITEMS; ++it) acc[it] = 0.0f;

    for (int n = 0; n < NCAM; ++n) {
        __syncthreads();
        stage_pairs(hm + (((size_t)b * NCAM + n) * J_ + j) * HW_, s_img, tid);
        __syncthreads();
        const unsigned short* __restrict__ ap = addr16 + n * NB + bin0;
        const uint2* __restrict__ wp = wpk + n * NB + bin0;
#pragma unroll
        for (int it = 0; it < ITEMS; ++it) {
            const int r = it * TPB + tid;     // coalesced
            if (r < BPB) {                    // last row partial (16000 = 15*1024+640)
                acc[it] += sample_pair(s_img, ap[r], wp[r].x, wp[r].y);
            }
        }
    }

    float* __restrict__ o = out + (size_t)bj * NB + bin0;
#pragma unroll
    for (int it = 0; it < ITEMS; ++it) {
        const int r = it * TPB + tid;
        if (r < BPB) o[r] = fminf(fmaxf(acc[it], 0.0f), 1.0f);  // 1/5 in weights
    }
}

// Fallback (tiny ws): R1-style f32-LDS kernel, inline weights. 600 blocks.
#define FB_SMEM   (HW_ * 4)
#define FB_NCHUNK 5
#define FB_BPB    (NB / FB_NCHUNK)   // 25600
#define FB_ITEMS  (FB_BPB / TPB)     // 25
__global__ __launch_bounds__(TPB) void project_fallback(
    const float* __restrict__ hm,
    const float* __restrict__ sgrid,
    float* __restrict__ out)
{
    extern __shared__ float s_f32[];
    const int tid   = threadIdx.x;
    const int bj    = blockIdx.x % NBJ;
    const int chunk = blockIdx.x / NBJ;
    const int b     = bj / J_;
    const int j     = bj % J_;
    const int bin0  = chunk * FB_BPB;

    float acc[FB_ITEMS];
#pragma unroll
    for (int it = 0; it < FB_ITEMS; ++it) acc[it] = 0.0f;

    for (int n = 0; n < NCAM; ++n) {
        __syncthreads();
        const float4* __restrict__ src =
            (const float4*)(hm + (((size_t)b * NCAM + n) * J_ + j) * HW_);
        float4* dst = (float4*)s_f32;
        for (int i = tid; i < HW_ / 4; i += TPB) dst[i] = src[i];
        __syncthreads();
        const float2* __restrict__ g2 = (const float2*)sgrid + n * NB + bin0;
#pragma unroll
        for (int it = 0; it < FB_ITEMS; ++it) {
            const float2 g = g2[it * TPB + tid];
            const float ix = (g.x + 1.0f) * (0.5f * (W_ - 1));
            const float iy = (g.y + 1.0f) * (0.5f * (H_ - 1));
            const float x0f = floorf(ix), y0f = floorf(iy);
            const float wx1 = ix - x0f, wx0 = 1.0f - wx1;
            const float wy1 = iy - y0f, wy0 = 1.0f - wy1;
            const int x0 = (int)x0f, y0 = (int)y0f;
            const int xc = min(max(x0, 0), W_ - 2);
            const int yc = min(max(y0, 0), H_ - 2);
            const float vx0 = (x0 >= 0  && x0 <= W_ - 1) ? wx0 : 0.0f;
            const float vx1 = (x0 >= -1 && x0 <= W_ - 2) ? wx1 : 0.0f;
            const float vy0 = (y0 >= 0  && y0 <= H_ - 1) ? wy0 : 0.0f;
            const float vy1 = (y0 >= -1 && y0 <= H_ - 2) ? wy1 : 0.0f;
            const bool xhi = (x0 == W_ - 1), xlo = (x0 == -1);
            const bool yhi = (y0 == H_ - 1), ylo = (y0 == -1);
            const float a0 = (xhi ? 0.0f : vx0) + (xlo ? vx1 : 0.0f);
            const float a1 = (xhi ? vx0 : 0.0f) + (xlo ? 0.0f : vx1);
            const float b0 = (yhi ? 0.0f : vy0) + (ylo ? vy1 : 0.0f);
            const float b1 = (yhi ? vy0 : 0.0f) + (ylo ? 0.0f : vy1);
            const float* r0 = s_f32 + (yc * W_ + xc);
            acc[it] += b0 * (a0 * r0[0] + a1 * r0[1])
                     + b1 * (a0 * r0[W_] + a1 * r0[W_ + 1]);
        }
    }
    float* __restrict__ o = out + (size_t)bj * NB + bin0;
#pragma unroll
    for (int it = 0; it < FB_ITEMS; ++it)
        o[it * TPB + tid] = fminf(fmaxf(acc[it] * 0.2f, 0.0f), 1.0f);
}

extern "C" void kernel_launch(void* const* d_in, const int* in_sizes, int n_in,
                              void* d_out, int out_size, void* d_ws, size_t ws_size,
                              hipStream_t stream) {
    const float* hm = (const float*)d_in[0];   // [8,5,15,128,240] f32
    const float* sg = (const float*)d_in[1];   // [5,128000,2] f32
    float* out = (float*)d_out;                // [8,15,128000] f32

    (void)hipFuncSetAttribute((const void*)project_fallback,
                              hipFuncAttributeMaxDynamicSharedMemorySize, FB_SMEM);

    const size_t addr_bytes = (size_t)NCAM * NB * sizeof(unsigned short); // 1.28 MB
    const size_t wpk_bytes  = (size_t)NCAM * NB * sizeof(uint2);          // 5.12 MB
    if (ws_size >= addr_bytes + wpk_bytes) {
        unsigned short* addr16 = (unsigned short*)d_ws;
        uint2* wpk = (uint2*)((char*)d_ws + addr_bytes);
        weights_kernel<<<(NCAM * NB + 255) / 256, 256, 0, stream>>>(sg, addr16, wpk);
        project_kernel<<<NBLK, TPB, SMEM_BYTES, stream>>>(hm, addr16, wpk, out);
    } else {
        project_fallback<<<NBJ * FB_NCHUNK, TPB, FB_SMEM, stream>>>(hm, sg, out);
    }
}